// Round 2
// baseline (3116.649 us; speedup 1.0000x reference)
//
#include <hip/hip_runtime.h>
#include <stdint.h>

#define DIM      2048
#define BATCH    16384
#define S_E      0.1f
#define S_C      0.1f
#define S_N      0.05f
#define DIVC     0.38f
#define NCAP     10.0f

typedef __attribute__((ext_vector_type(4))) float floatx4;
typedef __attribute__((ext_vector_type(8))) short short8;
typedef __attribute__((ext_vector_type(4))) short short4v;

__device__ __forceinline__ float bf2f(unsigned short u) {
  union { float f; unsigned v; } x; x.v = ((unsigned)u) << 16; return x.f;
}
__device__ __forceinline__ unsigned short f2bf(float f) {
  union { float f; unsigned v; } x; x.f = f;
  unsigned r = x.v + 0x7FFFu + ((x.v >> 16) & 1u);   // RNE
  return (unsigned short)(r >> 16);
}

__device__ __forceinline__ void gload_lds16(const void* g, void* l) {
  __builtin_amdgcn_global_load_lds((const __attribute__((address_space(1))) void*)g,
                                   (__attribute__((address_space(3))) void*)l,
                                   16, 0, 0);
}

// ---- dtype detector: flag=1 -> inputs are fp32, flag=0 -> bf16 ----
// bf16 N(0,1) half-words never have biased exp >= 0x84 (|x|>=32); fp32 low
// half-words are ~uniform 16-bit -> hit with p~0.48 per even element.
__global__ void k_detect(const unsigned short* __restrict__ h0u, int* __restrict__ flag) {
  const int lane = threadIdx.x;             // 64 threads, one wave
  int bad = 0;
#pragma unroll
  for (int i = 0; i < 32; ++i) {
    const unsigned u = h0u[lane + i * 64];
    const unsigned e = (u >> 7) & 0xFF;
    bad |= (e >= 0x84);
  }
  const unsigned long long m = __ballot(bad);
  if (lane == 0) *flag = (m != 0ull) ? 1 : 0;
}

// ---- canonicalize W1/W2 -> bf16 ----
__global__ __launch_bounds__(256) void k_prep_w(
    const void* __restrict__ w1r, const void* __restrict__ w2r,
    const int* __restrict__ flag,
    unsigned short* __restrict__ W1b, unsigned short* __restrict__ W2b) {
  const void* src = blockIdx.y ? w2r : w1r;
  unsigned short* dst = blockIdx.y ? W2b : W1b;
  const long i4 = (long)blockIdx.x * 256 + threadIdx.x;   // 4-elem group, 1048576 groups
  if (*flag) {
    const float4 v = ((const float4*)src)[i4];
    short4v o;
    o.x = (short)f2bf(v.x); o.y = (short)f2bf(v.y);
    o.z = (short)f2bf(v.z); o.w = (short)f2bf(v.w);
    ((short4v*)dst)[i4] = o;
  } else {
    ((short4v*)dst)[i4] = ((const short4v*)src)[i4];
  }
}

// ---- canonicalize biases -> fp32, anchors -> normalized fp32 dirs ----
__global__ __launch_bounds__(256) void k_prep_small(
    const void* __restrict__ b1r, const void* __restrict__ b2r,
    const void* __restrict__ a0r, const void* __restrict__ a1r,
    const void* __restrict__ a2r, const int* __restrict__ flag,
    float* __restrict__ b1f, float* __restrict__ b2f, float* __restrict__ dirs) {
  __shared__ float red[4];
  const int tid = threadIdx.x, wave = tid >> 6, lane = tid & 63;
  const int isf32 = *flag;
#pragma unroll
  for (int i = 0; i < 8; ++i) {
    const int idx = i * 256 + tid;
    b1f[idx] = isf32 ? ((const float*)b1r)[idx] : bf2f(((const unsigned short*)b1r)[idx]);
    b2f[idx] = isf32 ? ((const float*)b2r)[idx] : bf2f(((const unsigned short*)b2r)[idx]);
  }
  const void* ar[3] = { a0r, a1r, a2r };
  for (int a = 0; a < 3; ++a) {
    float v[8]; float s = 0.f;
#pragma unroll
    for (int i = 0; i < 8; ++i) {
      const int idx = i * 256 + tid;
      v[i] = isf32 ? ((const float*)ar[a])[idx] : bf2f(((const unsigned short*)ar[a])[idx]);
      s = fmaf(v[i], v[i], s);
    }
#pragma unroll
    for (int off = 32; off >= 1; off >>= 1) s += __shfl_xor(s, off);
    if (lane == 0) red[wave] = s;
    __syncthreads();
    const float S = red[0] + red[1] + red[2] + red[3];
    const float inv = 1.f / fmaxf(sqrtf(S), 1e-12f);
#pragma unroll
    for (int i = 0; i < 8; ++i) dirs[a * DIM + i * 256 + tid] = v[i] * inv;
    __syncthreads();
  }
}

// collapse coefficients from row stats (unit dirs: ||h-d||^2 = S0 - 2 h.d + 1)
__device__ __forceinline__ float4 row_coef(float S0, float Se, float Sc, float Sn) {
  const float Li = 1.f / fmaxf(sqrtf(S0), 1e-12f);
  const float ce = S_E * (DIVC - Se * Li) / fmaxf(sqrtf(fmaxf(S0 - 2.f * Se + 1.f, 0.f)), 1e-12f);
  const float cc = S_C * (DIVC - Sc * Li) / fmaxf(sqrtf(fmaxf(S0 - 2.f * Sc + 1.f, 0.f)), 1e-12f);
  const float cn = S_N * (DIVC - Sn * Li) / fmaxf(sqrtf(fmaxf(S0 - 2.f * Sn + 1.f, 0.f)), 1e-12f);
  float4 c; c.x = 1.f - (ce + cc + cn); c.y = ce; c.z = cc; c.w = cn; return c;
}

__device__ __forceinline__ void reduce4(float* red, int wave, int lane,
                                        float& s0, float& s1, float& s2, float& s3) {
#pragma unroll
  for (int off = 32; off >= 1; off >>= 1) {
    s0 += __shfl_xor(s0, off); s1 += __shfl_xor(s1, off);
    s2 += __shfl_xor(s2, off); s3 += __shfl_xor(s3, off);
  }
  if (lane == 0) { red[wave*4+0]=s0; red[wave*4+1]=s1; red[wave*4+2]=s2; red[wave*4+3]=s3; }
  __syncthreads();
  s0 = red[0] + red[4] + red[8]  + red[12];
  s1 = red[1] + red[5] + red[9]  + red[13];
  s2 = red[2] + red[6] + red[10] + red[14];
  s3 = red[3] + red[7] + red[11] + red[15];
}

// ---- bootstrap: h0 -> hf (fp32 master, FULL) + hb (bf16) + coefs ----
template<int FULL>
__global__ __launch_bounds__(256) void k_boot(
    const void* __restrict__ h0raw, const int* __restrict__ flag,
    const float* __restrict__ dirs, float* __restrict__ hf,
    unsigned short* __restrict__ hb, float4* __restrict__ coef) {
  __shared__ float red[16];
  const long row = blockIdx.x;
  const int tid = threadIdx.x, wave = tid >> 6, lane = tid & 63;
  const int isf32 = *flag;
  float h[8];
  float s0 = 0.f, se = 0.f, sc = 0.f, sn = 0.f;
#pragma unroll
  for (int i = 0; i < 2; ++i) {
    const int c4 = i * 256 + tid;
    float4 hv;
    if (isf32) {
      hv = ((const float4*)h0raw + row * (DIM/4))[c4];
    } else {
      const short4v hs = ((const short4v*)h0raw + row * (DIM/4))[c4];
      hv.x = bf2f((unsigned short)hs.x); hv.y = bf2f((unsigned short)hs.y);
      hv.z = bf2f((unsigned short)hs.z); hv.w = bf2f((unsigned short)hs.w);
    }
    const float4 ev = ((const float4*)dirs)[c4];
    const float4 cv = ((const float4*)(dirs + DIM))[c4];
    const float4 nv = ((const float4*)(dirs + 2*DIM))[c4];
    h[i*4+0]=hv.x; h[i*4+1]=hv.y; h[i*4+2]=hv.z; h[i*4+3]=hv.w;
    s0 = fmaf(hv.x,hv.x,fmaf(hv.y,hv.y,fmaf(hv.z,hv.z,fmaf(hv.w,hv.w,s0))));
    se = fmaf(hv.x,ev.x,fmaf(hv.y,ev.y,fmaf(hv.z,ev.z,fmaf(hv.w,ev.w,se))));
    sc = fmaf(hv.x,cv.x,fmaf(hv.y,cv.y,fmaf(hv.z,cv.z,fmaf(hv.w,cv.w,sc))));
    sn = fmaf(hv.x,nv.x,fmaf(hv.y,nv.y,fmaf(hv.z,nv.z,fmaf(hv.w,nv.w,sn))));
  }
  reduce4(red, wave, lane, s0, se, sc, sn);
  if (tid == 0) coef[row] = row_coef(s0, se, sc, sn);
#pragma unroll
  for (int i = 0; i < 2; ++i) {
    const int c4 = i * 256 + tid;
    if (FULL) {
      float4 o; o.x=h[i*4+0]; o.y=h[i*4+1]; o.z=h[i*4+2]; o.w=h[i*4+3];
      ((float4*)hf + row * (DIM/4))[c4] = o;
    }
    short4v ob;
    ob.x=(short)f2bf(h[i*4+0]); ob.y=(short)f2bf(h[i*4+1]);
    ob.z=(short)f2bf(h[i*4+2]); ob.w=(short)f2bf(h[i*4+3]);
    ((short4v*)hb + row * (DIM/4))[c4] = ob;
  }
}

// ---- GEMM1: T = tanh(hb @ W1^T + b1), m97 structure, 128x128 tile ----
__global__ __launch_bounds__(256) void gemm_tanh(
    const unsigned short* __restrict__ A, const unsigned short* __restrict__ B,
    const float* __restrict__ bias, unsigned short* __restrict__ Cb) {
  __shared__ short As[128 * 64];
  __shared__ short Bs[128 * 64];
  const int tid = threadIdx.x, wave = tid >> 6, lane = tid & 63;
  const int quad = lane >> 4, l16 = lane & 15;
  const int wm = (wave >> 1) * 64, wn = (wave & 1) * 64;
  const long m0 = (long)blockIdx.y * 128, n0 = (long)blockIdx.x * 128;
  floatx4 acc[4][4] = {};
  const int srow = tid >> 3, scol = (tid & 7) * 8;
  const unsigned short* Ag = A + (m0 + srow) * DIM + scol;
  const unsigned short* Bg = B + (n0 + srow) * DIM + scol;
  short* Al = As + tid * 8;
  short* Bl = Bs + tid * 8;
  for (int k0 = 0; k0 < DIM; k0 += 64) {
#pragma unroll
    for (int j = 0; j < 4; ++j) {
      gload_lds16(Ag + (long)(j * 32) * DIM + k0, Al + j * 2048);
      gload_lds16(Bg + (long)(j * 32) * DIM + k0, Bl + j * 2048);
    }
    __syncthreads();
#pragma unroll
    for (int kk = 0; kk < 64; kk += 32) {
      short8 af[4], bfr[4];
#pragma unroll
      for (int i = 0; i < 4; ++i)
        af[i] = *(const short8*)(As + (wm + i*16 + l16) * 64 + kk + quad * 8);
#pragma unroll
      for (int j = 0; j < 4; ++j)
        bfr[j] = *(const short8*)(Bs + (wn + j*16 + l16) * 64 + kk + quad * 8);
#pragma unroll
      for (int i = 0; i < 4; ++i)
#pragma unroll
        for (int j = 0; j < 4; ++j)
          acc[i][j] = __builtin_amdgcn_mfma_f32_16x16x32_bf16(af[i], bfr[j], acc[i][j], 0, 0, 0);
    }
    __syncthreads();
  }
#pragma unroll
  for (int j = 0; j < 4; ++j) {
    const long ncol = n0 + wn + j * 16 + l16;
    const float bv = bias[ncol];
#pragma unroll
    for (int i = 0; i < 4; ++i) {
      const long r0 = m0 + wm + i * 16 + quad * 4;
#pragma unroll
      for (int r = 0; r < 4; ++r) {
        const float x = acc[i][j][r] + bv;
        const float t = 1.f - 2.f / (__expf(2.f * x) + 1.f);
        Cb[(r0 + r) * DIM + ncol] = f2bf(t);
      }
    }
  }
}

// ---- GEMM2 + fused collapse update (in-place on h, pre-cap) ----
template<int FULL>
__global__ __launch_bounds__(256) void gemm_update(
    const unsigned short* __restrict__ A, const unsigned short* __restrict__ B,
    const float* __restrict__ bias, float* __restrict__ hf,
    unsigned short* __restrict__ hb, const float4* __restrict__ coef,
    const float* __restrict__ dirs) {
  __shared__ short As[128 * 64];
  __shared__ short Bs[128 * 64];
  const int tid = threadIdx.x, wave = tid >> 6, lane = tid & 63;
  const int quad = lane >> 4, l16 = lane & 15;
  const int wm = (wave >> 1) * 64, wn = (wave & 1) * 64;
  const long m0 = (long)blockIdx.y * 128, n0 = (long)blockIdx.x * 128;
  floatx4 acc[4][4] = {};
  const int srow = tid >> 3, scol = (tid & 7) * 8;
  const unsigned short* Ag = A + (m0 + srow) * DIM + scol;
  const unsigned short* Bg = B + (n0 + srow) * DIM + scol;
  short* Al = As + tid * 8;
  short* Bl = Bs + tid * 8;
  for (int k0 = 0; k0 < DIM; k0 += 64) {
#pragma unroll
    for (int j = 0; j < 4; ++j) {
      gload_lds16(Ag + (long)(j * 32) * DIM + k0, Al + j * 2048);
      gload_lds16(Bg + (long)(j * 32) * DIM + k0, Bl + j * 2048);
    }
    __syncthreads();
#pragma unroll
    for (int kk = 0; kk < 64; kk += 32) {
      short8 af[4], bfr[4];
#pragma unroll
      for (int i = 0; i < 4; ++i)
        af[i] = *(const short8*)(As + (wm + i*16 + l16) * 64 + kk + quad * 8);
#pragma unroll
      for (int j = 0; j < 4; ++j)
        bfr[j] = *(const short8*)(Bs + (wn + j*16 + l16) * 64 + kk + quad * 8);
#pragma unroll
      for (int i = 0; i < 4; ++i)
#pragma unroll
        for (int j = 0; j < 4; ++j)
          acc[i][j] = __builtin_amdgcn_mfma_f32_16x16x32_bf16(af[i], bfr[j], acc[i][j], 0, 0, 0);
    }
    __syncthreads();
  }
  // epilogue: h_pre = (T W2^T + b2) + ch*h + ce*e + cc*c + cn*n   (in place)
#pragma unroll
  for (int j = 0; j < 4; ++j) {
    const long ncol = n0 + wn + j * 16 + l16;
    const float bv = bias[ncol];
    const float de = dirs[ncol], dc = dirs[DIM + ncol], dn = dirs[2*DIM + ncol];
#pragma unroll
    for (int i = 0; i < 4; ++i) {
      const long r0 = m0 + wm + i * 16 + quad * 4;
#pragma unroll
      for (int r = 0; r < 4; ++r) {
        const float4 cf = coef[r0 + r];
        const long idx = (r0 + r) * DIM + ncol;
        const float hv = FULL ? hf[idx] : bf2f(hb[idx]);
        float v = acc[i][j][r] + bv;
        v = fmaf(cf.x, hv, v);
        v = fmaf(cf.y, de, v);
        v = fmaf(cf.z, dc, v);
        v = fmaf(cf.w, dn, v);
        if (FULL) hf[idx] = v; else hb[idx] = f2bf(v);
      }
    }
  }
}

// ---- cap: norm-clip h, refresh bf16 mirror, compute next-layer coefs ----
template<int FULL>
__global__ __launch_bounds__(256) void k_cap(
    float* __restrict__ hf, unsigned short* __restrict__ hb,
    float4* __restrict__ coef, const float* __restrict__ dirs,
    const int* __restrict__ flag, void* __restrict__ dout, int last) {
  __shared__ float red[16];
  const long row = blockIdx.x;
  const int tid = threadIdx.x, wave = tid >> 6, lane = tid & 63;
  float h[8];
  float s0 = 0.f, se = 0.f, sc = 0.f, sn = 0.f;
#pragma unroll
  for (int i = 0; i < 2; ++i) {
    const int c4 = i * 256 + tid;
    float4 hv;
    if (FULL) {
      hv = ((const float4*)hf + row * (DIM/4))[c4];
    } else {
      const short4v hs = ((const short4v*)hb + row * (DIM/4))[c4];
      hv.x = bf2f((unsigned short)hs.x); hv.y = bf2f((unsigned short)hs.y);
      hv.z = bf2f((unsigned short)hs.z); hv.w = bf2f((unsigned short)hs.w);
    }
    const float4 ev = ((const float4*)dirs)[c4];
    const float4 cv = ((const float4*)(dirs + DIM))[c4];
    const float4 nv = ((const float4*)(dirs + 2*DIM))[c4];
    h[i*4+0]=hv.x; h[i*4+1]=hv.y; h[i*4+2]=hv.z; h[i*4+3]=hv.w;
    s0 = fmaf(hv.x,hv.x,fmaf(hv.y,hv.y,fmaf(hv.z,hv.z,fmaf(hv.w,hv.w,s0))));
    se = fmaf(hv.x,ev.x,fmaf(hv.y,ev.y,fmaf(hv.z,ev.z,fmaf(hv.w,ev.w,se))));
    sc = fmaf(hv.x,cv.x,fmaf(hv.y,cv.y,fmaf(hv.z,cv.z,fmaf(hv.w,cv.w,sc))));
    sn = fmaf(hv.x,nv.x,fmaf(hv.y,nv.y,fmaf(hv.z,nv.z,fmaf(hv.w,nv.w,sn))));
  }
  reduce4(red, wave, lane, s0, se, sc, sn);
  const float nrm = sqrtf(s0);
  const float s = (nrm > NCAP) ? (NCAP / (nrm + 1e-8f)) : 1.f;
  if (tid == 0) coef[row] = row_coef(s0 * s * s, se * s, sc * s, sn * s);
  const int isf32 = *flag;
#pragma unroll
  for (int i = 0; i < 2; ++i) {
    const int c4 = i * 256 + tid;
    float4 o;
    o.x = h[i*4+0]*s; o.y = h[i*4+1]*s; o.z = h[i*4+2]*s; o.w = h[i*4+3]*s;
    if (FULL) ((float4*)hf + row * (DIM/4))[c4] = o;
    short4v ob;
    ob.x=(short)f2bf(o.x); ob.y=(short)f2bf(o.y);
    ob.z=(short)f2bf(o.z); ob.w=(short)f2bf(o.w);
    ((short4v*)hb + row * (DIM/4))[c4] = ob;
    if (last) {
      if (isf32) ((float4*)dout + row * (DIM/4))[c4] = o;
      else       ((short4v*)dout + row * (DIM/4))[c4] = ob;
    }
  }
}

extern "C" void kernel_launch(void* const* d_in, const int* in_sizes, int n_in,
                              void* d_out, int out_size, void* d_ws, size_t ws_size,
                              hipStream_t stream) {
  const void* h0  = d_in[0];
  const void* A_e = d_in[1];
  const void* A_c = d_in[2];
  const void* A_n = d_in[3];
  const void* W1  = d_in[4];
  const void* b1  = d_in[5];
  const void* W2  = d_in[6];
  const void* b2  = d_in[7];

  char* base = (char*)d_ws;
  size_t off = 0;
  auto take = [&](size_t n) -> char* {
    char* p = base + off; off += (n + 255) & ~(size_t)255; return p;
  };
  int*            flag = (int*)take(4);
  float*          dirs = (float*)take(3 * DIM * 4);
  float*          b1f  = (float*)take(DIM * 4);
  float*          b2f  = (float*)take(DIM * 4);
  float4*         coef = (float4*)take((size_t)BATCH * 16);
  unsigned short* W1b  = (unsigned short*)take((size_t)DIM * DIM * 2);
  unsigned short* W2b  = (unsigned short*)take((size_t)DIM * DIM * 2);
  unsigned short* T    = (unsigned short*)take((size_t)BATCH * DIM * 2);
  unsigned short* hb   = (unsigned short*)take((size_t)BATCH * DIM * 2);
  float*          hf   = (float*)take((size_t)BATCH * DIM * 4);
  const size_t need_full = off;
  const bool full = (ws_size >= need_full);   // else: bf16-master compact (151 MB)

  k_detect<<<1, 64, 0, stream>>>((const unsigned short*)h0, flag);
  k_prep_w<<<dim3(4096, 2), 256, 0, stream>>>(W1, W2, flag, W1b, W2b);
  k_prep_small<<<1, 256, 0, stream>>>(b1, b2, A_e, A_c, A_n, flag, b1f, b2f, dirs);

  const dim3 gg(DIM / 128, BATCH / 128);
  if (full) {
    k_boot<1><<<BATCH, 256, 0, stream>>>(h0, flag, dirs, hf, hb, coef);
    for (int L = 0; L < 4; ++L) {
      gemm_tanh<<<gg, 256, 0, stream>>>(hb, W1b, b1f, T);
      gemm_update<1><<<gg, 256, 0, stream>>>(T, W2b, b2f, hf, hb, coef, dirs);
      k_cap<1><<<BATCH, 256, 0, stream>>>(hf, hb, coef, dirs, flag, d_out, (L == 3) ? 1 : 0);
    }
  } else {
    k_boot<0><<<BATCH, 256, 0, stream>>>(h0, flag, dirs, nullptr, hb, coef);
    for (int L = 0; L < 4; ++L) {
      gemm_tanh<<<gg, 256, 0, stream>>>(hb, W1b, b1f, T);
      gemm_update<0><<<gg, 256, 0, stream>>>(T, W2b, b2f, nullptr, hb, coef, dirs);
      k_cap<0><<<BATCH, 256, 0, stream>>>(nullptr, hb, coef, dirs, flag, d_out, (L == 3) ? 1 : 0);
    }
  }
}

// Round 3
// 1858.078 us; speedup vs baseline: 1.6774x; 1.6774x over previous
//
#include <hip/hip_runtime.h>
#include <stdint.h>

#define DIM      2048
#define BATCH    16384
#define S_E      0.1f
#define S_C      0.1f
#define S_N      0.05f
#define DIVC     0.38f
#define NCAP     10.0f

typedef __attribute__((ext_vector_type(4))) float floatx4;
typedef __attribute__((ext_vector_type(8))) short short8;
typedef __attribute__((ext_vector_type(4))) short short4v;

__device__ __forceinline__ float bf2f(unsigned short u) {
  union { float f; unsigned v; } x; x.v = ((unsigned)u) << 16; return x.f;
}
__device__ __forceinline__ unsigned short f2bf(float f) {
  union { float f; unsigned v; } x; x.f = f;
  unsigned r = x.v + 0x7FFFu + ((x.v >> 16) & 1u);   // RNE
  return (unsigned short)(r >> 16);
}

__device__ __forceinline__ void gload_lds16(const void* g, void* l) {
  __builtin_amdgcn_global_load_lds((const __attribute__((address_space(1))) void*)g,
                                   (__attribute__((address_space(3))) void*)l,
                                   16, 0, 0);
}

// ---- dtype detector: flag=1 -> fp32 inputs, flag=0 -> bf16 ----
__global__ void k_detect(const unsigned short* __restrict__ h0u, int* __restrict__ flag) {
  const int lane = threadIdx.x;
  int bad = 0;
#pragma unroll
  for (int i = 0; i < 32; ++i) {
    const unsigned u = h0u[lane + i * 64];
    const unsigned e = (u >> 7) & 0xFF;
    bad |= (e >= 0x84);
  }
  const unsigned long long m = __ballot(bad);
  if (lane == 0) *flag = (m != 0ull) ? 1 : 0;
}

__global__ __launch_bounds__(256) void k_prep_w(
    const void* __restrict__ w1r, const void* __restrict__ w2r,
    const int* __restrict__ flag,
    unsigned short* __restrict__ W1b, unsigned short* __restrict__ W2b) {
  const void* src = blockIdx.y ? w2r : w1r;
  unsigned short* dst = blockIdx.y ? W2b : W1b;
  const long i4 = (long)blockIdx.x * 256 + threadIdx.x;
  if (*flag) {
    const float4 v = ((const float4*)src)[i4];
    short4v o;
    o.x = (short)f2bf(v.x); o.y = (short)f2bf(v.y);
    o.z = (short)f2bf(v.z); o.w = (short)f2bf(v.w);
    ((short4v*)dst)[i4] = o;
  } else {
    ((short4v*)dst)[i4] = ((const short4v*)src)[i4];
  }
}

__global__ __launch_bounds__(256) void k_prep_small(
    const void* __restrict__ b1r, const void* __restrict__ b2r,
    const void* __restrict__ a0r, const void* __restrict__ a1r,
    const void* __restrict__ a2r, const int* __restrict__ flag,
    float* __restrict__ b1f, float* __restrict__ b2f, float* __restrict__ dirs) {
  __shared__ float red[4];
  const int tid = threadIdx.x, wave = tid >> 6, lane = tid & 63;
  const int isf32 = *flag;
#pragma unroll
  for (int i = 0; i < 8; ++i) {
    const int idx = i * 256 + tid;
    b1f[idx] = isf32 ? ((const float*)b1r)[idx] : bf2f(((const unsigned short*)b1r)[idx]);
    b2f[idx] = isf32 ? ((const float*)b2r)[idx] : bf2f(((const unsigned short*)b2r)[idx]);
  }
  const void* ar[3] = { a0r, a1r, a2r };
  for (int a = 0; a < 3; ++a) {
    float v[8]; float s = 0.f;
#pragma unroll
    for (int i = 0; i < 8; ++i) {
      const int idx = i * 256 + tid;
      v[i] = isf32 ? ((const float*)ar[a])[idx] : bf2f(((const unsigned short*)ar[a])[idx]);
      s = fmaf(v[i], v[i], s);
    }
#pragma unroll
    for (int off = 32; off >= 1; off >>= 1) s += __shfl_xor(s, off);
    if (lane == 0) red[wave] = s;
    __syncthreads();
    const float S = red[0] + red[1] + red[2] + red[3];
    const float inv = 1.f / fmaxf(sqrtf(S), 1e-12f);
#pragma unroll
    for (int i = 0; i < 8; ++i) dirs[a * DIM + i * 256 + tid] = v[i] * inv;
    __syncthreads();
  }
}

// coefs from CAPPED row stats (unit dirs: ||h-d||^2 = S0 - 2 h.d + 1)
__device__ __forceinline__ float4 row_coef(float S0, float Se, float Sc, float Sn) {
  const float Li = 1.f / fmaxf(sqrtf(S0), 1e-12f);
  const float ce = S_E * (DIVC - Se * Li) / fmaxf(sqrtf(fmaxf(S0 - 2.f * Se + 1.f, 0.f)), 1e-12f);
  const float cc = S_C * (DIVC - Sc * Li) / fmaxf(sqrtf(fmaxf(S0 - 2.f * Sc + 1.f, 0.f)), 1e-12f);
  const float cn = S_N * (DIVC - Sn * Li) / fmaxf(sqrtf(fmaxf(S0 - 2.f * Sn + 1.f, 0.f)), 1e-12f);
  float4 c; c.x = 1.f - (ce + cc + cn); c.y = ce; c.z = cc; c.w = cn; return c;
}

// ---- boot: h0 -> hf (FULL) + hb + coef (s=1) + scl=1 ----
template<int FULL>
__global__ __launch_bounds__(256) void k_boot(
    const void* __restrict__ h0raw, const int* __restrict__ flag,
    const float* __restrict__ dirs, float* __restrict__ hf,
    unsigned short* __restrict__ hb, float4* __restrict__ coef,
    float* __restrict__ scl) {
  __shared__ float red[16];
  const long row = blockIdx.x;
  const int tid = threadIdx.x, wave = tid >> 6, lane = tid & 63;
  const int isf32 = *flag;
  float h[8];
  float s0 = 0.f, se = 0.f, sc = 0.f, sn = 0.f;
#pragma unroll
  for (int i = 0; i < 2; ++i) {
    const int c4 = i * 256 + tid;
    float4 hv;
    if (isf32) {
      hv = ((const float4*)h0raw + row * (DIM/4))[c4];
    } else {
      const short4v hs = ((const short4v*)h0raw + row * (DIM/4))[c4];
      hv.x = bf2f((unsigned short)hs.x); hv.y = bf2f((unsigned short)hs.y);
      hv.z = bf2f((unsigned short)hs.z); hv.w = bf2f((unsigned short)hs.w);
    }
    const float4 ev = ((const float4*)dirs)[c4];
    const float4 cv = ((const float4*)(dirs + DIM))[c4];
    const float4 nv = ((const float4*)(dirs + 2*DIM))[c4];
    h[i*4+0]=hv.x; h[i*4+1]=hv.y; h[i*4+2]=hv.z; h[i*4+3]=hv.w;
    s0 = fmaf(hv.x,hv.x,fmaf(hv.y,hv.y,fmaf(hv.z,hv.z,fmaf(hv.w,hv.w,s0))));
    se = fmaf(hv.x,ev.x,fmaf(hv.y,ev.y,fmaf(hv.z,ev.z,fmaf(hv.w,ev.w,se))));
    sc = fmaf(hv.x,cv.x,fmaf(hv.y,cv.y,fmaf(hv.z,cv.z,fmaf(hv.w,cv.w,sc))));
    sn = fmaf(hv.x,nv.x,fmaf(hv.y,nv.y,fmaf(hv.z,nv.z,fmaf(hv.w,nv.w,sn))));
  }
#pragma unroll
  for (int off = 32; off >= 1; off >>= 1) {
    s0 += __shfl_xor(s0, off); se += __shfl_xor(se, off);
    sc += __shfl_xor(sc, off); sn += __shfl_xor(sn, off);
  }
  if (lane == 0) { red[wave*4+0]=s0; red[wave*4+1]=se; red[wave*4+2]=sc; red[wave*4+3]=sn; }
  __syncthreads();
  if (tid == 0) {
    const float S0 = red[0]+red[4]+red[8]+red[12];
    const float Se = red[1]+red[5]+red[9]+red[13];
    const float Sc = red[2]+red[6]+red[10]+red[14];
    const float Sn = red[3]+red[7]+red[11]+red[15];
    coef[row] = row_coef(S0, Se, Sc, Sn);   // h0 is not pre-capped; s=1
    scl[row] = 1.f;
  }
#pragma unroll
  for (int i = 0; i < 2; ++i) {
    const int c4 = i * 256 + tid;
    if (FULL) {
      float4 o; o.x=h[i*4+0]; o.y=h[i*4+1]; o.z=h[i*4+2]; o.w=h[i*4+3];
      ((float4*)hf + row * (DIM/4))[c4] = o;
    }
    short4v ob;
    ob.x=(short)f2bf(h[i*4+0]); ob.y=(short)f2bf(h[i*4+1]);
    ob.z=(short)f2bf(h[i*4+2]); ob.w=(short)f2bf(h[i*4+3]);
    ((short4v*)hb + row * (DIM/4))[c4] = ob;
  }
}

// ---- GEMM1: T = tanh(scl[row]*(hb @ W1^T) + b1) ----
// XOR-swizzled LDS (chunk c of row r at position c^(r&7)), LDS-transposed store.
__global__ __launch_bounds__(256, 3) void gemm_tanh(
    const unsigned short* __restrict__ A, const unsigned short* __restrict__ B,
    const float* __restrict__ bias, const float* __restrict__ scl,
    unsigned short* __restrict__ Cb) {
  __shared__ __align__(16) char smem[32768];
  short* As = (short*)smem;             // [128][64]
  short* Bs = (short*)(smem + 16384);
  short* Eh = (short*)smem;             // epilogue: [128][128] bf16
  const int tid = threadIdx.x, wave = tid >> 6, lane = tid & 63;
  const int quad = lane >> 4, l16 = lane & 15;
  const int sw = l16 & 7;
  const int wm = (wave >> 1) * 64, wn = (wave & 1) * 64;
  const long m0 = (long)blockIdx.y * 128, n0 = (long)blockIdx.x * 128;
  floatx4 acc[4][4] = {};
  const int srow = tid >> 3;
  const int scol = (((tid & 7) ^ (srow & 7))) * 8;     // swizzled source chunk
  const unsigned short* Ag = A + (m0 + srow) * DIM + scol;
  const unsigned short* Bg = B + (n0 + srow) * DIM + scol;
  short* Al = As + tid * 8;
  short* Bl = Bs + tid * 8;
  for (int k0 = 0; k0 < DIM; k0 += 64) {
#pragma unroll
    for (int j = 0; j < 4; ++j) {
      gload_lds16(Ag + (long)(j * 32) * DIM + k0, Al + j * 2048);
      gload_lds16(Bg + (long)(j * 32) * DIM + k0, Bl + j * 2048);
    }
    __syncthreads();
#pragma unroll
    for (int kk = 0; kk < 64; kk += 32) {
      short8 af[4], bfr[4];
#pragma unroll
      for (int i = 0; i < 4; ++i)
        af[i] = *(const short8*)(As + (wm + i*16 + l16) * 64 + ((((kk>>3) + quad) ^ sw) * 8));
#pragma unroll
      for (int j = 0; j < 4; ++j)
        bfr[j] = *(const short8*)(Bs + (wn + j*16 + l16) * 64 + ((((kk>>3) + quad) ^ sw) * 8));
#pragma unroll
      for (int i = 0; i < 4; ++i)
#pragma unroll
        for (int j = 0; j < 4; ++j)
          acc[i][j] = __builtin_amdgcn_mfma_f32_16x16x32_bf16(af[i], bfr[j], acc[i][j], 0, 0, 0);
    }
    __syncthreads();
  }
  // scale rows, bias, tanh -> bf16 into LDS, then coalesced 16B stores
  float sr[16];
#pragma unroll
  for (int i = 0; i < 4; ++i)
#pragma unroll
    for (int r = 0; r < 4; ++r)
      sr[i*4+r] = scl[m0 + wm + i*16 + quad*4 + r];
#pragma unroll
  for (int j = 0; j < 4; ++j) {
    const int col = wn + j*16 + l16;
    const float bv = bias[n0 + col];
#pragma unroll
    for (int i = 0; i < 4; ++i) {
      const int row = wm + i*16 + quad*4;
#pragma unroll
      for (int r = 0; r < 4; ++r) {
        const float x = fmaf(sr[i*4+r], acc[i][j][r], bv);
        const float t = 1.f - 2.f / (__expf(2.f * x) + 1.f);
        Eh[(row + r) * 128 + col] = (short)f2bf(t);
      }
    }
  }
  __syncthreads();
#pragma unroll
  for (int t = 0; t < 8; ++t) {
    const int g = tid + 256 * t;
    const int row = g >> 4, c8 = (g & 15) * 8;
    const short8 v = *(const short8*)(Eh + row * 128 + c8);
    *(short8*)(Cb + (m0 + row) * DIM + n0 + c8) = v;
  }
}

// ---- GEMM2 + fused collapse update (uncapped h master; cf.x = ch*s folded) ----
template<int FULL>
__global__ __launch_bounds__(256, 3) void gemm_update(
    const unsigned short* __restrict__ A, const unsigned short* __restrict__ B,
    const float* __restrict__ bias, float* __restrict__ hf,
    unsigned short* __restrict__ hb, const float4* __restrict__ coef,
    const float* __restrict__ dirs) {
  __shared__ __align__(16) char smem[32768];
  short* As = (short*)smem;
  short* Bs = (short*)(smem + 16384);
  float* Ef = (float*)smem;             // epilogue: [128][64] fp32 (half-tile)
  const int tid = threadIdx.x, wave = tid >> 6, lane = tid & 63;
  const int quad = lane >> 4, l16 = lane & 15;
  const int sw = l16 & 7;
  const int wm = (wave >> 1) * 64, wn = (wave & 1) * 64;
  const long m0 = (long)blockIdx.y * 128, n0 = (long)blockIdx.x * 128;
  floatx4 acc[4][4] = {};
  const int srow = tid >> 3;
  const int scol = (((tid & 7) ^ (srow & 7))) * 8;
  const unsigned short* Ag = A + (m0 + srow) * DIM + scol;
  const unsigned short* Bg = B + (n0 + srow) * DIM + scol;
  short* Al = As + tid * 8;
  short* Bl = Bs + tid * 8;
  for (int k0 = 0; k0 < DIM; k0 += 64) {
#pragma unroll
    for (int j = 0; j < 4; ++j) {
      gload_lds16(Ag + (long)(j * 32) * DIM + k0, Al + j * 2048);
      gload_lds16(Bg + (long)(j * 32) * DIM + k0, Bl + j * 2048);
    }
    __syncthreads();
#pragma unroll
    for (int kk = 0; kk < 64; kk += 32) {
      short8 af[4], bfr[4];
#pragma unroll
      for (int i = 0; i < 4; ++i)
        af[i] = *(const short8*)(As + (wm + i*16 + l16) * 64 + ((((kk>>3) + quad) ^ sw) * 8));
#pragma unroll
      for (int j = 0; j < 4; ++j)
        bfr[j] = *(const short8*)(Bs + (wn + j*16 + l16) * 64 + ((((kk>>3) + quad) ^ sw) * 8));
#pragma unroll
      for (int i = 0; i < 4; ++i)
#pragma unroll
        for (int j = 0; j < 4; ++j)
          acc[i][j] = __builtin_amdgcn_mfma_f32_16x16x32_bf16(af[i], bfr[j], acc[i][j], 0, 0, 0);
    }
    __syncthreads();
  }
  // two half-tiles through LDS; coalesced float4 RMW of hf + short4 hb mirror
#pragma unroll
  for (int hh = 0; hh < 2; ++hh) {
    __syncthreads();
#pragma unroll
    for (int j2 = 0; j2 < 2; ++j2) {
      const int j = hh * 2 + j2;
      const int cc = (wn >> 1) + j2 * 16 + l16;         // [0,64)
#pragma unroll
      for (int i = 0; i < 4; ++i) {
        const int row = wm + i*16 + quad*4;
#pragma unroll
        for (int r = 0; r < 4; ++r)
          Ef[(row + r) * 64 + cc] = acc[i][j][r];
      }
    }
    __syncthreads();
#pragma unroll
    for (int t = 0; t < 8; ++t) {
      const int g = tid + 256 * t;
      const int row = g >> 4, cc4 = (g & 15) * 4;
      const int col = hh * 32 + cc4 + (cc4 & 32);       // de-compact two 32-spans
      const long gr = m0 + row, gc = n0 + col;
      const float4 e  = *(const float4*)(Ef + row * 64 + cc4);
      const float4 bv = *(const float4*)(bias + gc);
      const float4 de = *(const float4*)(dirs + gc);
      const float4 dc = *(const float4*)(dirs + DIM + gc);
      const float4 dn = *(const float4*)(dirs + 2*DIM + gc);
      const float4 cf = coef[gr];
      float4 hv;
      if (FULL) {
        hv = *(const float4*)(hf + gr * DIM + gc);
      } else {
        const short4v hs = *(const short4v*)(hb + gr * DIM + gc);
        hv.x = bf2f((unsigned short)hs.x); hv.y = bf2f((unsigned short)hs.y);
        hv.z = bf2f((unsigned short)hs.z); hv.w = bf2f((unsigned short)hs.w);
      }
      float4 v;
      v.x = e.x + bv.x; v.y = e.y + bv.y; v.z = e.z + bv.z; v.w = e.w + bv.w;
      v.x = fmaf(cf.x, hv.x, v.x); v.y = fmaf(cf.x, hv.y, v.y);
      v.z = fmaf(cf.x, hv.z, v.z); v.w = fmaf(cf.x, hv.w, v.w);
      v.x = fmaf(cf.y, de.x, v.x); v.y = fmaf(cf.y, de.y, v.y);
      v.z = fmaf(cf.y, de.z, v.z); v.w = fmaf(cf.y, de.w, v.w);
      v.x = fmaf(cf.z, dc.x, v.x); v.y = fmaf(cf.z, dc.y, v.y);
      v.z = fmaf(cf.z, dc.z, v.z); v.w = fmaf(cf.z, dc.w, v.w);
      v.x = fmaf(cf.w, dn.x, v.x); v.y = fmaf(cf.w, dn.y, v.y);
      v.z = fmaf(cf.w, dn.z, v.z); v.w = fmaf(cf.w, dn.w, v.w);
      if (FULL) *(float4*)(hf + gr * DIM + gc) = v;
      short4v ob;
      ob.x = (short)f2bf(v.x); ob.y = (short)f2bf(v.y);
      ob.z = (short)f2bf(v.z); ob.w = (short)f2bf(v.w);
      *(short4v*)(hb + gr * DIM + gc) = ob;
    }
  }
}

// ---- stats: read hb (uncapped), emit next-layer coef (cf.x=ch*s) + scl=s ----
__global__ __launch_bounds__(256) void k_stats(
    const unsigned short* __restrict__ hb, const float* __restrict__ dirs,
    float4* __restrict__ coef, float* __restrict__ scl) {
  const int tid = threadIdx.x, w = tid >> 6, lane = tid & 63;
  const long row = (long)blockIdx.x * 4 + w;
  const unsigned short* hr = hb + row * DIM;
  float s0 = 0.f, se = 0.f, sc = 0.f, sn = 0.f;
#pragma unroll
  for (int i = 0; i < 4; ++i) {
    const int o = i * 512 + lane * 8;
    const short8 h8 = *(const short8*)(hr + o);
    float h[8];
#pragma unroll
    for (int q = 0; q < 8; ++q) h[q] = bf2f((unsigned short)h8[q]);
    const float4 e0 = *(const float4*)(dirs + o),       e1 = *(const float4*)(dirs + o + 4);
    const float4 c0 = *(const float4*)(dirs + DIM + o), c1 = *(const float4*)(dirs + DIM + o + 4);
    const float4 n0v = *(const float4*)(dirs + 2*DIM + o), n1 = *(const float4*)(dirs + 2*DIM + o + 4);
    const float ee[8] = { e0.x,e0.y,e0.z,e0.w, e1.x,e1.y,e1.z,e1.w };
    const float ccv[8] = { c0.x,c0.y,c0.z,c0.w, c1.x,c1.y,c1.z,c1.w };
    const float nn[8] = { n0v.x,n0v.y,n0v.z,n0v.w, n1.x,n1.y,n1.z,n1.w };
#pragma unroll
    for (int q = 0; q < 8; ++q) {
      s0 = fmaf(h[q], h[q], s0);
      se = fmaf(h[q], ee[q], se);
      sc = fmaf(h[q], ccv[q], sc);
      sn = fmaf(h[q], nn[q], sn);
    }
  }
#pragma unroll
  for (int off = 32; off >= 1; off >>= 1) {
    s0 += __shfl_xor(s0, off); se += __shfl_xor(se, off);
    sc += __shfl_xor(sc, off); sn += __shfl_xor(sn, off);
  }
  if (lane == 0) {
    const float nrm = sqrtf(s0);
    const float s = (nrm > NCAP) ? (NCAP / (nrm + 1e-8f)) : 1.f;
    float4 cf = row_coef(s0 * s * s, se * s, sc * s, sn * s);
    cf.x *= s;                       // applied to UNCAPPED h master
    coef[row] = cf;
    scl[row] = s;
  }
}

// ---- finish: norm-cap final h_pre, write d_out (dtype by flag) ----
template<int FULL>
__global__ __launch_bounds__(256) void k_finish(
    const float* __restrict__ hf, const unsigned short* __restrict__ hb,
    const int* __restrict__ flag, void* __restrict__ dout) {
  const int tid = threadIdx.x, w = tid >> 6, lane = tid & 63;
  const long row = (long)blockIdx.x * 4 + w;
  float4 hv[8];
  float s0 = 0.f;
#pragma unroll
  for (int i = 0; i < 8; ++i) {
    const int o = i * 256 + lane * 4;
    if (FULL) {
      hv[i] = *(const float4*)(hf + row * DIM + o);
    } else {
      const short4v hs = *(const short4v*)(hb + row * DIM + o);
      hv[i].x = bf2f((unsigned short)hs.x); hv[i].y = bf2f((unsigned short)hs.y);
      hv[i].z = bf2f((unsigned short)hs.z); hv[i].w = bf2f((unsigned short)hs.w);
    }
    s0 = fmaf(hv[i].x,hv[i].x,fmaf(hv[i].y,hv[i].y,fmaf(hv[i].z,hv[i].z,fmaf(hv[i].w,hv[i].w,s0))));
  }
#pragma unroll
  for (int off = 32; off >= 1; off >>= 1) s0 += __shfl_xor(s0, off);
  const float nrm = sqrtf(s0);
  const float s = (nrm > NCAP) ? (NCAP / (nrm + 1e-8f)) : 1.f;
  const int isf32 = *flag;
#pragma unroll
  for (int i = 0; i < 8; ++i) {
    const int o = i * 256 + lane * 4;
    float4 v;
    v.x = hv[i].x * s; v.y = hv[i].y * s; v.z = hv[i].z * s; v.w = hv[i].w * s;
    if (isf32) {
      *((float4*)dout + (row * DIM + o) / 4) = v;
    } else {
      short4v ob;
      ob.x = (short)f2bf(v.x); ob.y = (short)f2bf(v.y);
      ob.z = (short)f2bf(v.z); ob.w = (short)f2bf(v.w);
      *((short4v*)dout + (row * DIM + o) / 4) = ob;
    }
  }
}

extern "C" void kernel_launch(void* const* d_in, const int* in_sizes, int n_in,
                              void* d_out, int out_size, void* d_ws, size_t ws_size,
                              hipStream_t stream) {
  const void* h0  = d_in[0];
  const void* A_e = d_in[1];
  const void* A_c = d_in[2];
  const void* A_n = d_in[3];
  const void* W1  = d_in[4];
  const void* b1  = d_in[5];
  const void* W2  = d_in[6];
  const void* b2  = d_in[7];

  char* base = (char*)d_ws;
  size_t off = 0;
  auto take = [&](size_t n) -> char* {
    char* p = base + off; off += (n + 255) & ~(size_t)255; return p;
  };
  int*            flag = (int*)take(4);
  float*          dirs = (float*)take(3 * DIM * 4);
  float*          b1f  = (float*)take(DIM * 4);
  float*          b2f  = (float*)take(DIM * 4);
  float4*         coef = (float4*)take((size_t)BATCH * 16);
  float*          scl  = (float*)take((size_t)BATCH * 4);
  unsigned short* W1b  = (unsigned short*)take((size_t)DIM * DIM * 2);
  unsigned short* W2b  = (unsigned short*)take((size_t)DIM * DIM * 2);
  unsigned short* T    = (unsigned short*)take((size_t)BATCH * DIM * 2);
  unsigned short* hb   = (unsigned short*)take((size_t)BATCH * DIM * 2);
  float*          hf   = (float*)take((size_t)BATCH * DIM * 4);   // LAST (fallback drops it)
  const size_t need_full = off;
  const bool full = (ws_size >= need_full);

  k_detect<<<1, 64, 0, stream>>>((const unsigned short*)h0, flag);
  k_prep_w<<<dim3(4096, 2), 256, 0, stream>>>(W1, W2, flag, W1b, W2b);
  k_prep_small<<<1, 256, 0, stream>>>(b1, b2, A_e, A_c, A_n, flag, b1f, b2f, dirs);

  const dim3 gg(DIM / 128, BATCH / 128);
  if (full) {
    k_boot<1><<<BATCH, 256, 0, stream>>>(h0, flag, dirs, hf, hb, coef, scl);
    for (int L = 0; L < 4; ++L) {
      gemm_tanh<<<gg, 256, 0, stream>>>(hb, W1b, b1f, scl, T);
      gemm_update<1><<<gg, 256, 0, stream>>>(T, W2b, b2f, hf, hb, coef, dirs);
      if (L < 3) k_stats<<<BATCH/4, 256, 0, stream>>>(hb, dirs, coef, scl);
    }
    k_finish<1><<<BATCH/4, 256, 0, stream>>>(hf, hb, flag, d_out);
  } else {
    k_boot<0><<<BATCH, 256, 0, stream>>>(h0, flag, dirs, nullptr, hb, coef, scl);
    for (int L = 0; L < 4; ++L) {
      gemm_tanh<<<gg, 256, 0, stream>>>(hb, W1b, b1f, scl, T);
      gemm_update<0><<<gg, 256, 0, stream>>>(T, W2b, b2f, nullptr, hb, coef, dirs);
      if (L < 3) k_stats<<<BATCH/4, 256, 0, stream>>>(hb, dirs, coef, scl);
    }
    k_finish<0><<<BATCH/4, 256, 0, stream>>>(nullptr, hb, flag, d_out);
  }
}